// Round 3
// baseline (793.461 us; speedup 1.0000x reference)
//
#include <hip/hip_runtime.h>
#include <hip/hip_bf16.h>
#include <cstddef>

#define B_    64
#define NPG   1024
#define F_    128
#define K_    128
#define E_    16384
#define N_    (B_*NPG)        // 65536
#define BE_   (B_*E_)         // 1048576
#define ADJ_DIM 8192
#define ADJ_ELEMS 67108864UL  // 8192*8192

// ---------------- edge counting ----------------
__global__ void k_count(const int* __restrict__ srcl, const int* __restrict__ dstl,
                        int* __restrict__ deg_in, int* __restrict__ deg_out) {
  int i = blockIdx.x * 256 + threadIdx.x;
  int b = i >> 14;           // / E_
  int base = b << 10;        // * NPG
  atomicAdd(&deg_in[dstl[i] + base], 1);
  atomicAdd(&deg_out[srcl[i] + base], 1);
}

// ---------------- per-graph exclusive scan (1024 nodes/graph, 1 block/graph) ----------------
__global__ __launch_bounds__(1024) void k_scan(const int* __restrict__ deg,
                                               int* __restrict__ off, int* __restrict__ cur) {
  int b = blockIdx.x, t = threadIdx.x;
  int v = deg[b * NPG + t];
  int lane = t & 63, wid = t >> 6;
  int x = v;
  #pragma unroll
  for (int d = 1; d < 64; d <<= 1) {
    int y = __shfl_up(x, d, 64);
    if (lane >= d) x += y;
  }
  __shared__ int wsum[16];
  if (lane == 63) wsum[wid] = x;
  __syncthreads();
  if (t < 16) {
    int s = wsum[t];
    #pragma unroll
    for (int d = 1; d < 16; d <<= 1) {
      int y = __shfl_up(s, d, 16);
      if (t >= d) s += y;
    }
    wsum[t] = s;
  }
  __syncthreads();
  int woff = wid ? wsum[wid - 1] : 0;
  int o = b * E_ + woff + x - v;   // exclusive scan, graph base b*E
  off[b * NPG + t] = o;
  cur[b * NPG + t] = o;
}

// ---------------- CSR fill ----------------
__global__ void k_build(const int* __restrict__ srcl, const int* __restrict__ dstl,
                        int* __restrict__ cur_in, int* __restrict__ cur_out,
                        int* __restrict__ ebd_src, int* __restrict__ ebs_dst) {
  int i = blockIdx.x * 256 + threadIdx.x;
  int b = i >> 14;
  int base = b << 10;
  int s = srcl[i] + base, d = dstl[i] + base;
  int p = atomicAdd(&cur_in[d], 1);
  ebd_src[p] = s;
  int q = atomicAdd(&cur_out[s], 1);
  ebs_dst[q] = d;
}

// ---------------- gather-accumulate (c and AS). one wave per node ----------------
template<int STRIDE, bool MEAN>
__global__ void k_gather(const float* __restrict__ rows, const int* __restrict__ elist,
                         const int* __restrict__ off, const int* __restrict__ deg,
                         float* __restrict__ out) {
  int w = threadIdx.x >> 6, lane = threadIdx.x & 63;
  int node = blockIdx.x * 4 + w;
  int o = off[node], d = deg[node];
  float accx = 0.f, accy = 0.f;
  int e = o, end = o + d;
  while (e < end) {
    int cnt = end - e; if (cnt > 64) cnt = 64;
    int sidx = (lane < cnt) ? elist[e + lane] : 0;
    for (int j = 0; j < cnt; ++j) {
      int s = __shfl(sidx, j, 64);
      const float2 v = *reinterpret_cast<const float2*>(rows + (size_t)s * STRIDE + lane * 2);
      accx += v.x; accy += v.y;
    }
    e += cnt;
  }
  if (MEAN) {
    float inv = 1.0f / fmaxf((float)d, 1.0f);
    accx *= inv; accy *= inv;
  }
  *reinterpret_cast<float2*>(out + (size_t)node * 128 + lane * 2) = make_float2(accx, accy);
}

// ---------------- Z = [h|c] @ W + b  (M=65536, K=256, N=128 per blockIdx.y) ----------------
__global__ __launch_bounds__(256) void k_gemm(const float* __restrict__ h,
                                              const float* __restrict__ c,
                                              const float* __restrict__ Wf,
                                              const float* __restrict__ Wp,
                                              const float* __restrict__ bf,
                                              const float* __restrict__ bp,
                                              float* __restrict__ Z) {
  const int m0 = blockIdx.x * 128;
  const float* __restrict__ W = blockIdx.y ? Wp : Wf;
  const float* __restrict__ bias = blockIdx.y ? bp : bf;
  const int j0 = blockIdx.y * 128;
  __shared__ float As[16][128];  // [k][m]
  __shared__ float Bs[16][128];  // [k][j]
  const int t = threadIdx.x;
  const int tx = t & 15, ty = t >> 4;
  float acc[8][8];
  #pragma unroll
  for (int i = 0; i < 8; ++i)
    #pragma unroll
    for (int j = 0; j < 8; ++j) acc[i][j] = 0.f;

  for (int kc = 0; kc < 256; kc += 16) {
    const float* __restrict__ X = (kc < 128) ? h : c;
    const int kb = kc & 127;
    #pragma unroll
    for (int r = 0; r < 2; ++r) {
      int idx = t * 2 + r;
      int row = idx >> 2;
      int kq = (idx & 3) * 4;
      const float4 v = *reinterpret_cast<const float4*>(X + (size_t)(m0 + row) * 128 + kb + kq);
      As[kq + 0][row] = v.x;
      As[kq + 1][row] = v.y;
      As[kq + 2][row] = v.z;
      As[kq + 3][row] = v.w;
    }
    #pragma unroll
    for (int r = 0; r < 2; ++r) {
      int idx = t * 2 + r;
      int kk = idx >> 5;
      int jq = (idx & 31) * 4;
      *reinterpret_cast<float4*>(&Bs[kk][jq]) =
          *reinterpret_cast<const float4*>(W + (size_t)(kc + kk) * 128 + jq);
    }
    __syncthreads();
    #pragma unroll
    for (int kk = 0; kk < 16; ++kk) {
      float a[8], b[8];
      #pragma unroll
      for (int i = 0; i < 8; ++i) a[i] = As[kk][ty * 8 + i];
      #pragma unroll
      for (int j = 0; j < 8; ++j) b[j] = Bs[kk][tx * 8 + j];
      #pragma unroll
      for (int i = 0; i < 8; ++i)
        #pragma unroll
        for (int j = 0; j < 8; ++j) acc[i][j] += a[i] * b[j];
    }
    __syncthreads();
  }
  #pragma unroll
  for (int i = 0; i < 8; ++i) {
    size_t m = (size_t)(m0 + ty * 8 + i);
    float4 o0 = make_float4(acc[i][0] + bias[tx * 8 + 0], acc[i][1] + bias[tx * 8 + 1],
                            acc[i][2] + bias[tx * 8 + 2], acc[i][3] + bias[tx * 8 + 3]);
    float4 o1 = make_float4(acc[i][4] + bias[tx * 8 + 4], acc[i][5] + bias[tx * 8 + 5],
                            acc[i][6] + bias[tx * 8 + 6], acc[i][7] + bias[tx * 8 + 7]);
    *reinterpret_cast<float4*>(Z + m * 256 + j0 + tx * 8) = o0;
    *reinterpret_cast<float4*>(Z + m * 256 + j0 + tx * 8 + 4) = o1;
  }
}

// ---------------- per-row l2norm/relu (feat) and l2norm/relu/softmax (assign), in place ----------------
__global__ void k_norm(float* __restrict__ Z) {
  int w = threadIdx.x >> 6, lane = threadIdx.x & 63;
  int node = blockIdx.x * 4 + w;
  float* row = Z + (size_t)node * 256;

  float2 zf = *reinterpret_cast<float2*>(row + lane * 2);
  float ss = zf.x * zf.x + zf.y * zf.y;
  #pragma unroll
  for (int d = 32; d >= 1; d >>= 1) ss += __shfl_xor(ss, d, 64);
  float r1 = 1.0f / fmaxf(sqrtf(ss), 1e-12f);
  *reinterpret_cast<float2*>(row + lane * 2) =
      make_float2(fmaxf(zf.x * r1, 0.f), fmaxf(zf.y * r1, 0.f));

  float2 zp = *reinterpret_cast<float2*>(row + 128 + lane * 2);
  float s2 = zp.x * zp.x + zp.y * zp.y;
  #pragma unroll
  for (int d = 32; d >= 1; d >>= 1) s2 += __shfl_xor(s2, d, 64);
  float r2 = 1.0f / fmaxf(sqrtf(s2), 1e-12f);
  float vx = fmaxf(zp.x * r2, 0.f), vy = fmaxf(zp.y * r2, 0.f);
  float mx = fmaxf(vx, vy);
  #pragma unroll
  for (int d = 32; d >= 1; d >>= 1) mx = fmaxf(mx, __shfl_xor(mx, d, 64));
  float ex = __expf(vx - mx), ey = __expf(vy - mx);
  float es = ex + ey;
  #pragma unroll
  for (int d = 32; d >= 1; d >>= 1) es += __shfl_xor(es, d, 64);
  float inv = 1.0f / es;
  *reinterpret_cast<float2*>(row + 128 + lane * 2) = make_float2(ex * inv, ey * inv);
}

// ---------------- per-graph S^T X partials: blk = b*4 + ch*2 + nh ----------------
__global__ __launch_bounds__(256) void k_pool(const float* __restrict__ Z,
                                              const float* __restrict__ AS,
                                              float* __restrict__ part) {
  const int blk = blockIdx.x;
  const int b = blk >> 2, ch = (blk >> 1) & 1, nh = blk & 1;
  const int n0 = b * NPG + nh * 512;
  __shared__ float Ss[16][128];
  __shared__ float Xs[16][128];
  const int t = threadIdx.x;
  const int tx = t & 15, ty = t >> 4;
  float acc[8][8];
  #pragma unroll
  for (int i = 0; i < 8; ++i)
    #pragma unroll
    for (int j = 0; j < 8; ++j) acc[i][j] = 0.f;

  for (int nc = 0; nc < 512; nc += 16) {
    #pragma unroll
    for (int r = 0; r < 2; ++r) {
      int idx = t * 2 + r;
      int nn = idx >> 5;
      int jq = (idx & 31) * 4;
      int n = n0 + nc + nn;
      *reinterpret_cast<float4*>(&Ss[nn][jq]) =
          *reinterpret_cast<const float4*>(Z + (size_t)n * 256 + 128 + jq);
      if (ch == 0) {
        *reinterpret_cast<float4*>(&Xs[nn][jq]) =
            *reinterpret_cast<const float4*>(Z + (size_t)n * 256 + jq);
      } else {
        *reinterpret_cast<float4*>(&Xs[nn][jq]) =
            *reinterpret_cast<const float4*>(AS + (size_t)n * 128 + jq);
      }
    }
    __syncthreads();
    #pragma unroll
    for (int nn = 0; nn < 16; ++nn) {
      float a[8], x[8];
      #pragma unroll
      for (int i = 0; i < 8; ++i) a[i] = Ss[nn][ty * 8 + i];
      #pragma unroll
      for (int j = 0; j < 8; ++j) x[j] = Xs[nn][tx * 8 + j];
      #pragma unroll
      for (int i = 0; i < 8; ++i)
        #pragma unroll
        for (int j = 0; j < 8; ++j) acc[i][j] += a[i] * x[j];
    }
    __syncthreads();
  }
  float* dst = part + (size_t)blk * 16384;
  #pragma unroll
  for (int i = 0; i < 8; ++i) {
    *reinterpret_cast<float4*>(dst + (ty * 8 + i) * 128 + tx * 8) =
        make_float4(acc[i][0], acc[i][1], acc[i][2], acc[i][3]);
    *reinterpret_cast<float4*>(dst + (ty * 8 + i) * 128 + tx * 8 + 4) =
        make_float4(acc[i][4], acc[i][5], acc[i][6], acc[i][7]);
  }
}

// ---------------- combine nh partials -> h_new (final) and blocks (ws) ----------------
__global__ void k_reduce(const float* __restrict__ part, float* __restrict__ h_new,
                         float* __restrict__ blocks) {
  int i = blockIdx.x * 256 + threadIdx.x;   // 2,097,152
  int bc = i >> 14;                         // b*2 + ch
  int r = i & 16383;
  int b = bc >> 1, ch = bc & 1;
  float v = part[((size_t)(b * 4 + ch * 2 + 0)) * 16384 + r] +
            part[((size_t)(b * 4 + ch * 2 + 1)) * 16384 + r];
  if (ch == 0) h_new[(size_t)b * 16384 + r] = v;
  else blocks[(size_t)b * 16384 + r] = v;
}

// ---------------- scatter diagonal blocks into zeroed adj ----------------
__global__ void k_scatter(const float* __restrict__ blocks, float* __restrict__ adj) {
  int i = blockIdx.x * 256 + threadIdx.x;   // 1,048,576
  int b = i >> 14;
  int k = (i >> 7) & 127;
  int l = i & 127;
  adj[(size_t)(b * 128 + k) * ADJ_DIM + b * 128 + l] = blocks[i];
}

extern "C" void kernel_launch(void* const* d_in, const int* in_sizes, int n_in,
                              void* d_out, int out_size, void* d_ws, size_t ws_size,
                              hipStream_t stream) {
  (void)in_sizes; (void)n_in; (void)out_size; (void)ws_size;
  const float* h   = (const float*)d_in[0];
  const int* srcl  = (const int*)d_in[1];
  const int* dstl  = (const int*)d_in[2];
  const float* Wf  = (const float*)d_in[3];
  const float* bf  = (const float*)d_in[4];
  const float* Wp  = (const float*)d_in[5];
  const float* bp  = (const float*)d_in[6];

  float* out   = (float*)d_out;
  float* adj   = out;                    // 67,108,864 floats, used as scratch then zero+scatter
  float* h_new = out + ADJ_ELEMS;        // 1,048,576 floats (final)

  float* c    = adj;                     //  8,388,608 floats
  float* Z    = adj + 8388608UL;         // 16,777,216 floats  (feat | assign per row, stride 256)
  float* AS   = adj + 25165824UL;        //  8,388,608 floats
  float* part = adj + 33554432UL;        //  4,194,304 floats
  int* ebd_src = (int*)(adj + 37748736UL);  // 1,048,576 ints
  int* ebs_dst = (int*)(adj + 38797312UL);  // 1,048,576 ints

  int* deg_in  = (int*)d_ws;
  int* deg_out = deg_in + N_;
  int* off_in  = deg_out + N_;
  int* cur_in  = off_in + N_;
  int* off_out = cur_in + N_;
  int* cur_out = off_out + N_;
  float* blocks = (float*)(cur_out + N_);   // 1,048,576 floats

  hipMemsetAsync(deg_in, 0, 2UL * N_ * sizeof(int), stream);
  k_count<<<BE_ / 256, 256, 0, stream>>>(srcl, dstl, deg_in, deg_out);
  k_scan<<<B_, 1024, 0, stream>>>(deg_in, off_in, cur_in);
  k_scan<<<B_, 1024, 0, stream>>>(deg_out, off_out, cur_out);
  k_build<<<BE_ / 256, 256, 0, stream>>>(srcl, dstl, cur_in, cur_out, ebd_src, ebs_dst);
  k_gather<128, true><<<N_ / 4, 256, 0, stream>>>(h, ebd_src, off_in, deg_in, c);
  k_gemm<<<dim3(N_ / 128, 2), 256, 0, stream>>>(h, c, Wf, Wp, bf, bp, Z);
  k_norm<<<N_ / 4, 256, 0, stream>>>(Z);
  k_gather<256, false><<<N_ / 4, 256, 0, stream>>>(Z + 128, ebs_dst, off_out, deg_out, AS);
  k_pool<<<256, 256, 0, stream>>>(Z, AS, part);
  k_reduce<<<2097152 / 256, 256, 0, stream>>>(part, h_new, blocks);
  hipMemsetAsync(adj, 0, ADJ_ELEMS * sizeof(float), stream);
  k_scatter<<<1048576 / 256, 256, 0, stream>>>(blocks, adj);
}

// Round 4
// 713.053 us; speedup vs baseline: 1.1128x; 1.1128x over previous
//
#include <hip/hip_runtime.h>
#include <hip/hip_bf16.h>
#include <cstddef>

#define B_    64
#define NPG   1024
#define F_    128
#define K_    128
#define E_    16384
#define N_    (B_*NPG)        // 65536
#define BE_   (B_*E_)         // 1048576
#define ADJ_DIM 8192
#define ADJ_ELEMS 67108864UL  // 8192*8192

typedef __bf16 bf16x8 __attribute__((ext_vector_type(8)));
typedef float  f32x4  __attribute__((ext_vector_type(4)));

__device__ inline float b2f(unsigned short u) {
  return __uint_as_float(((unsigned)u) << 16);
}

// ---------------- edge counting ----------------
__global__ void k_count(const int* __restrict__ srcl, const int* __restrict__ dstl,
                        int* __restrict__ deg_in, int* __restrict__ deg_out) {
  int i = blockIdx.x * 256 + threadIdx.x;
  int b = i >> 14;
  int base = b << 10;
  atomicAdd(&deg_in[dstl[i] + base], 1);
  atomicAdd(&deg_out[srcl[i] + base], 1);
}

// ---------------- per-graph exclusive scan ----------------
__global__ __launch_bounds__(1024) void k_scan(const int* __restrict__ deg,
                                               int* __restrict__ off, int* __restrict__ cur) {
  int b = blockIdx.x, t = threadIdx.x;
  int v = deg[b * NPG + t];
  int lane = t & 63, wid = t >> 6;
  int x = v;
  #pragma unroll
  for (int d = 1; d < 64; d <<= 1) {
    int y = __shfl_up(x, d, 64);
    if (lane >= d) x += y;
  }
  __shared__ int wsum[16];
  if (lane == 63) wsum[wid] = x;
  __syncthreads();
  if (t < 16) {
    int s = wsum[t];
    #pragma unroll
    for (int d = 1; d < 16; d <<= 1) {
      int y = __shfl_up(s, d, 16);
      if (t >= d) s += y;
    }
    wsum[t] = s;
  }
  __syncthreads();
  int woff = wid ? wsum[wid - 1] : 0;
  int o = b * E_ + woff + x - v;
  off[b * NPG + t] = o;
  cur[b * NPG + t] = o;
}

// ---------------- CSR fill ----------------
__global__ void k_build(const int* __restrict__ srcl, const int* __restrict__ dstl,
                        int* __restrict__ cur_in, int* __restrict__ cur_out,
                        int* __restrict__ ebd_src, int* __restrict__ ebs_dst) {
  int i = blockIdx.x * 256 + threadIdx.x;
  int b = i >> 14;
  int base = b << 10;
  int s = srcl[i] + base, d = dstl[i] + base;
  int p = atomicAdd(&cur_in[d], 1);
  ebd_src[p] = s;
  int q = atomicAdd(&cur_out[s], 1);
  ebs_dst[q] = d;
}

// ---------------- gather fp32 rows (c = mean of in-neighbor h) ----------------
__global__ void k_gather_c(const float* __restrict__ rows, const int* __restrict__ elist,
                           const int* __restrict__ off, const int* __restrict__ deg,
                           float* __restrict__ out) {
  int w = threadIdx.x >> 6, lane = threadIdx.x & 63;
  int node = blockIdx.x * 4 + w;
  int o = off[node], d = deg[node];
  float accx = 0.f, accy = 0.f;
  int e = o, end = o + d;
  while (e < end) {
    int cnt = end - e; if (cnt > 64) cnt = 64;
    int sidx = (lane < cnt) ? elist[e + lane] : 0;
    for (int j = 0; j < cnt; ++j) {
      int s = __shfl(sidx, j, 64);
      const float2 v = *reinterpret_cast<const float2*>(rows + (size_t)s * 128 + lane * 2);
      accx += v.x; accy += v.y;
    }
    e += cnt;
  }
  float inv = 1.0f / fmaxf((float)d, 1.0f);
  accx *= inv; accy *= inv;
  *reinterpret_cast<float2*>(out + (size_t)node * 128 + lane * 2) = make_float2(accx, accy);
}

// ---------------- gather bf16 assign rows (AS) -> fp32 out ----------------
__global__ void k_gather_as(const unsigned short* __restrict__ rows, const int* __restrict__ elist,
                            const int* __restrict__ off, const int* __restrict__ deg,
                            float* __restrict__ out) {
  int w = threadIdx.x >> 6, lane = threadIdx.x & 63;
  int node = blockIdx.x * 4 + w;
  int o = off[node], d = deg[node];
  float accx = 0.f, accy = 0.f;
  int e = o, end = o + d;
  while (e < end) {
    int cnt = end - e; if (cnt > 64) cnt = 64;
    int sidx = (lane < cnt) ? elist[e + lane] : 0;
    for (int j = 0; j < cnt; ++j) {
      int s = __shfl(sidx, j, 64);
      unsigned v = *reinterpret_cast<const unsigned*>(rows + (size_t)s * 256 + lane * 2);
      accx += __uint_as_float((v & 0xffffu) << 16);
      accy += __uint_as_float(v & 0xffff0000u);
    }
    e += cnt;
  }
  *reinterpret_cast<float2*>(out + (size_t)node * 128 + lane * 2) = make_float2(accx, accy);
}

// ---------------- W transpose+cvt: Wt[j][k] bf16, j=0..255 (feat|pool), k=0..255 ----------------
__global__ void k_wt(const float* __restrict__ Wf, const float* __restrict__ Wp,
                     __bf16* __restrict__ Wt) {
  int j = blockIdx.x;          // 0..255
  int k = threadIdx.x;         // 0..255
  const float* W = (j < 128) ? Wf : Wp;
  int jj = j & 127;
  Wt[j * 256 + k] = (__bf16)W[k * 128 + jj];
}

// ---------------- MFMA GEMM: Z[n][256] = norm/relu(/softmax)([h|c] @ W + b), bf16 out ----------
// BM=128, BN=256 (cols 0-127 feat, 128-255 pool), K=256. 512 thr = 8 waves (4x2).
__global__ __launch_bounds__(512) void k_gemm(const float* __restrict__ h,
                                              const float* __restrict__ c,
                                              const __bf16* __restrict__ Wt,
                                              const float* __restrict__ bfeat,
                                              const float* __restrict__ bpool,
                                              __bf16* __restrict__ Z) {
  __shared__ char smem[69632];
  __bf16* A_lds = (__bf16*)smem;            // [128][32]
  __bf16* B_lds = (__bf16*)(smem + 8192);   // [256][40] padded rows (80B, 16-aligned)
  const int t = threadIdx.x;
  const int wid = t >> 6, lane = t & 63;
  const int wm = wid >> 1, wn = wid & 1;
  const int lo = lane & 15, hi = lane >> 4;
  const int m0 = blockIdx.x * 128;

  float bias[8];
  const float* bsrc = wn ? bpool : bfeat;
  #pragma unroll
  for (int nf = 0; nf < 8; ++nf) bias[nf] = bsrc[nf * 16 + lo];

  f32x4 acc[2][8];
  #pragma unroll
  for (int mf = 0; mf < 2; ++mf)
    #pragma unroll
    for (int nf = 0; nf < 8; ++nf) acc[mf][nf] = (f32x4){0.f, 0.f, 0.f, 0.f};

  const int am = t >> 2, akq = (t & 3) * 8;        // A staging: thread -> (m, k-octet pair)
  const int bj = t >> 1, bh = (t & 1) * 16;        // B staging: thread -> (col, 16-elem half)

  for (int ks = 0; ks < 8; ++ks) {
    const int kb = ks * 32;
    // ---- stage A (h or c fp32 -> bf16 LDS [m][k]) ----
    const float* __restrict__ X = (kb < 128) ? h : c;
    const int kbb = kb & 127;
    {
      const float4 v0 = *reinterpret_cast<const float4*>(X + (size_t)(m0 + am) * 128 + kbb + akq);
      const float4 v1 = *reinterpret_cast<const float4*>(X + (size_t)(m0 + am) * 128 + kbb + akq + 4);
      bf16x8 bv;
      bv[0] = (__bf16)v0.x; bv[1] = (__bf16)v0.y; bv[2] = (__bf16)v0.z; bv[3] = (__bf16)v0.w;
      bv[4] = (__bf16)v1.x; bv[5] = (__bf16)v1.y; bv[6] = (__bf16)v1.z; bv[7] = (__bf16)v1.w;
      *reinterpret_cast<bf16x8*>(A_lds + am * 32 + akq) = bv;
    }
    // ---- stage B (Wt bf16 [j][k] -> LDS [j][40]) ----
    {
      bf16x8 b0 = *reinterpret_cast<const bf16x8*>(Wt + bj * 256 + kb + bh);
      bf16x8 b1 = *reinterpret_cast<const bf16x8*>(Wt + bj * 256 + kb + bh + 8);
      *reinterpret_cast<bf16x8*>(B_lds + bj * 40 + bh) = b0;
      *reinterpret_cast<bf16x8*>(B_lds + bj * 40 + bh + 8) = b1;
    }
    __syncthreads();
    bf16x8 a[2], b[8];
    #pragma unroll
    for (int mf = 0; mf < 2; ++mf)
      a[mf] = *reinterpret_cast<const bf16x8*>(A_lds + (wm * 32 + mf * 16 + lo) * 32 + hi * 8);
    #pragma unroll
    for (int nf = 0; nf < 8; ++nf)
      b[nf] = *reinterpret_cast<const bf16x8*>(B_lds + (wn * 128 + nf * 16 + lo) * 40 + hi * 8);
    #pragma unroll
    for (int mf = 0; mf < 2; ++mf)
      #pragma unroll
      for (int nf = 0; nf < 8; ++nf)
        acc[mf][nf] = __builtin_amdgcn_mfma_f32_16x16x32_bf16(a[mf], b[nf], acc[mf][nf], 0, 0, 0);
    __syncthreads();
  }

  // ---- fused epilogue: bias + l2norm + relu (+ softmax on pool side), bf16 out via LDS ----
  __bf16* obuf = (__bf16*)(smem + wid * 8704);    // per-wave [32][136]
  #pragma unroll
  for (int mf = 0; mf < 2; ++mf) {
    #pragma unroll
    for (int r = 0; r < 4; ++r) {
      float v[8];
      #pragma unroll
      for (int nf = 0; nf < 8; ++nf) v[nf] = acc[mf][nf][r] + bias[nf];
      float ss = 0.f;
      #pragma unroll
      for (int nf = 0; nf < 8; ++nf) ss += v[nf] * v[nf];
      ss += __shfl_xor(ss, 1, 64); ss += __shfl_xor(ss, 2, 64);
      ss += __shfl_xor(ss, 4, 64); ss += __shfl_xor(ss, 8, 64);
      float rn = 1.0f / fmaxf(sqrtf(ss), 1e-12f);
      #pragma unroll
      for (int nf = 0; nf < 8; ++nf) v[nf] = fmaxf(v[nf] * rn, 0.f);
      if (wn) {
        float mx = v[0];
        #pragma unroll
        for (int nf = 1; nf < 8; ++nf) mx = fmaxf(mx, v[nf]);
        mx = fmaxf(mx, __shfl_xor(mx, 1, 64)); mx = fmaxf(mx, __shfl_xor(mx, 2, 64));
        mx = fmaxf(mx, __shfl_xor(mx, 4, 64)); mx = fmaxf(mx, __shfl_xor(mx, 8, 64));
        float es = 0.f;
        #pragma unroll
        for (int nf = 0; nf < 8; ++nf) { v[nf] = __expf(v[nf] - mx); es += v[nf]; }
        es += __shfl_xor(es, 1, 64); es += __shfl_xor(es, 2, 64);
        es += __shfl_xor(es, 4, 64); es += __shfl_xor(es, 8, 64);
        float inv = 1.0f / es;
        #pragma unroll
        for (int nf = 0; nf < 8; ++nf) v[nf] *= inv;
      }
      int row = mf * 16 + hi * 4 + r;
      #pragma unroll
      for (int nf = 0; nf < 8; ++nf) obuf[row * 136 + nf * 16 + lo] = (__bf16)v[nf];
    }
  }
  __syncthreads();
  #pragma unroll
  for (int i = 0; i < 8; ++i) {
    int r = i * 4 + hi;
    bf16x8 d = *reinterpret_cast<const bf16x8*>(obuf + r * 136 + lo * 8);
    int node = m0 + wm * 32 + r;
    *reinterpret_cast<bf16x8*>(Z + (size_t)node * 256 + wn * 128 + lo * 8) = d;
  }
}

// ---------------- per-graph S^T X partials (fp32 VALU, bf16 Z in) ----------------
__global__ __launch_bounds__(256) void k_pool(const unsigned short* __restrict__ Zb,
                                              const float* __restrict__ AS,
                                              float* __restrict__ part) {
  const int blk = blockIdx.x;
  const int b = blk >> 2, ch = (blk >> 1) & 1, nh = blk & 1;
  const int n0 = b * NPG + nh * 512;
  __shared__ float Ss[16][128];
  __shared__ float Xs[16][128];
  const int t = threadIdx.x;
  const int tx = t & 15, ty = t >> 4;
  float acc[8][8];
  #pragma unroll
  for (int i = 0; i < 8; ++i)
    #pragma unroll
    for (int j = 0; j < 8; ++j) acc[i][j] = 0.f;

  for (int nc = 0; nc < 512; nc += 16) {
    #pragma unroll
    for (int r = 0; r < 2; ++r) {
      int idx = t * 2 + r;
      int nn = idx >> 5;
      int jq = (idx & 31) * 4;
      int n = n0 + nc + nn;
      ushort4 sv = *reinterpret_cast<const ushort4*>(Zb + (size_t)n * 256 + 128 + jq);
      *reinterpret_cast<float4*>(&Ss[nn][jq]) =
          make_float4(b2f(sv.x), b2f(sv.y), b2f(sv.z), b2f(sv.w));
      if (ch == 0) {
        ushort4 xv = *reinterpret_cast<const ushort4*>(Zb + (size_t)n * 256 + jq);
        *reinterpret_cast<float4*>(&Xs[nn][jq]) =
            make_float4(b2f(xv.x), b2f(xv.y), b2f(xv.z), b2f(xv.w));
      } else {
        *reinterpret_cast<float4*>(&Xs[nn][jq]) =
            *reinterpret_cast<const float4*>(AS + (size_t)n * 128 + jq);
      }
    }
    __syncthreads();
    #pragma unroll
    for (int nn = 0; nn < 16; ++nn) {
      float a[8], x[8];
      #pragma unroll
      for (int i = 0; i < 8; ++i) a[i] = Ss[nn][ty * 8 + i];
      #pragma unroll
      for (int j = 0; j < 8; ++j) x[j] = Xs[nn][tx * 8 + j];
      #pragma unroll
      for (int i = 0; i < 8; ++i)
        #pragma unroll
        for (int j = 0; j < 8; ++j) acc[i][j] += a[i] * x[j];
    }
    __syncthreads();
  }
  float* dst = part + (size_t)blk * 16384;
  #pragma unroll
  for (int i = 0; i < 8; ++i) {
    *reinterpret_cast<float4*>(dst + (ty * 8 + i) * 128 + tx * 8) =
        make_float4(acc[i][0], acc[i][1], acc[i][2], acc[i][3]);
    *reinterpret_cast<float4*>(dst + (ty * 8 + i) * 128 + tx * 8 + 4) =
        make_float4(acc[i][4], acc[i][5], acc[i][6], acc[i][7]);
  }
}

// ---------------- combine partials -> h_new (final) and blocks (ws) ----------------
__global__ void k_reduce(const float* __restrict__ part, float* __restrict__ h_new,
                         float* __restrict__ blocks) {
  int i = blockIdx.x * 256 + threadIdx.x;
  int bc = i >> 14;
  int r = i & 16383;
  int b = bc >> 1, ch = bc & 1;
  float v = part[((size_t)(b * 4 + ch * 2 + 0)) * 16384 + r] +
            part[((size_t)(b * 4 + ch * 2 + 1)) * 16384 + r];
  if (ch == 0) h_new[(size_t)b * 16384 + r] = v;
  else blocks[(size_t)b * 16384 + r] = v;
}

// ---------------- scatter diagonal blocks into zeroed adj ----------------
__global__ void k_scatter(const float* __restrict__ blocks, float* __restrict__ adj) {
  int i = blockIdx.x * 256 + threadIdx.x;
  int b = i >> 14;
  int k = (i >> 7) & 127;
  int l = i & 127;
  adj[(size_t)(b * 128 + k) * ADJ_DIM + b * 128 + l] = blocks[i];
}

extern "C" void kernel_launch(void* const* d_in, const int* in_sizes, int n_in,
                              void* d_out, int out_size, void* d_ws, size_t ws_size,
                              hipStream_t stream) {
  (void)in_sizes; (void)n_in; (void)out_size; (void)ws_size;
  const float* h   = (const float*)d_in[0];
  const int* srcl  = (const int*)d_in[1];
  const int* dstl  = (const int*)d_in[2];
  const float* Wf  = (const float*)d_in[3];
  const float* bfe = (const float*)d_in[4];
  const float* Wp  = (const float*)d_in[5];
  const float* bpo = (const float*)d_in[6];

  float* out   = (float*)d_out;
  float* adj   = out;
  float* h_new = out + ADJ_ELEMS;

  float* c          = adj;                                  //  8,388,608 f
  __bf16* Z         = (__bf16*)(adj + 8388608UL);           // 16,777,216 bf16 (32 MB)
  float* AS         = adj + 16777216UL;                     //  8,388,608 f
  float* part       = adj + 25165824UL;                     //  4,194,304 f
  int* ebd_src      = (int*)(adj + 29360128UL);             //  1,048,576 i
  int* ebs_dst      = (int*)(adj + 30408704UL);             //  1,048,576 i
  __bf16* Wt        = (__bf16*)(adj + 31457280UL);          //     65,536 bf16

  int* deg_in  = (int*)d_ws;
  int* deg_out = deg_in + N_;
  int* off_in  = deg_out + N_;
  int* cur_in  = off_in + N_;
  int* off_out = cur_in + N_;
  int* cur_out = off_out + N_;
  float* blocks = (float*)(cur_out + N_);

  hipMemsetAsync(deg_in, 0, 2UL * N_ * sizeof(int), stream);
  k_wt<<<256, 256, 0, stream>>>(Wf, Wp, Wt);
  k_count<<<BE_ / 256, 256, 0, stream>>>(srcl, dstl, deg_in, deg_out);
  k_scan<<<B_, 1024, 0, stream>>>(deg_in, off_in, cur_in);
  k_scan<<<B_, 1024, 0, stream>>>(deg_out, off_out, cur_out);
  k_build<<<BE_ / 256, 256, 0, stream>>>(srcl, dstl, cur_in, cur_out, ebd_src, ebs_dst);
  k_gather_c<<<N_ / 4, 256, 0, stream>>>(h, ebd_src, off_in, deg_in, c);
  k_gemm<<<N_ / 128, 512, 0, stream>>>(h, c, Wt, bfe, bpo, Z);
  k_gather_as<<<N_ / 4, 256, 0, stream>>>((const unsigned short*)Z + 128, ebs_dst, off_out, deg_out, AS);
  k_pool<<<256, 256, 0, stream>>>((const unsigned short*)Z, AS, part);
  k_reduce<<<2097152 / 256, 256, 0, stream>>>(part, h_new, blocks);
  hipMemsetAsync(adj, 0, ADJ_ELEMS * sizeof(float), stream);
  k_scatter<<<1048576 / 256, 256, 0, stream>>>(blocks, adj);
}

// Round 6
// 654.152 us; speedup vs baseline: 1.2130x; 1.0900x over previous
//
#include <hip/hip_runtime.h>
#include <hip/hip_bf16.h>
#include <cstddef>

#define B_    64
#define NPG   1024
#define F_    128
#define K_    128
#define E_    16384
#define N_    (B_*NPG)        // 65536
#define BE_   (B_*E_)         // 1048576
#define ADJ_DIM 8192
#define ADJ_ELEMS 67108864UL  // 8192*8192

typedef __bf16 bf16x8 __attribute__((ext_vector_type(8)));
typedef float  f32x4  __attribute__((ext_vector_type(4)));

__device__ inline float b2f(unsigned short u) {
  return __uint_as_float(((unsigned)u) << 16);
}
__device__ inline unsigned short f2b(float f) {
  __bf16 b = (__bf16)f;
  return *reinterpret_cast<unsigned short*>(&b);
}

// ---------------- h -> bf16 ----------------
__global__ void k_hbf(const float* __restrict__ h, unsigned short* __restrict__ hb) {
  int i = blockIdx.x * 256 + threadIdx.x;   // 4 elems each, 8,388,608 total
  float4 v = reinterpret_cast<const float4*>(h)[i];
  ushort4 o;
  o.x = f2b(v.x); o.y = f2b(v.y); o.z = f2b(v.z); o.w = f2b(v.w);
  reinterpret_cast<ushort4*>(hb)[i] = o;
}

// ---------------- edge counting ----------------
__global__ void k_count(const int* __restrict__ srcl, const int* __restrict__ dstl,
                        int* __restrict__ deg_in, int* __restrict__ deg_out) {
  int i = blockIdx.x * 256 + threadIdx.x;
  int b = i >> 14;
  int base = b << 10;
  atomicAdd(&deg_in[dstl[i] + base], 1);
  atomicAdd(&deg_out[srcl[i] + base], 1);
}

// ---------------- per-graph exclusive scan ----------------
__global__ __launch_bounds__(1024) void k_scan(const int* __restrict__ deg,
                                               int* __restrict__ off, int* __restrict__ cur) {
  int b = blockIdx.x, t = threadIdx.x;
  int v = deg[b * NPG + t];
  int lane = t & 63, wid = t >> 6;
  int x = v;
  #pragma unroll
  for (int d = 1; d < 64; d <<= 1) {
    int y = __shfl_up(x, d, 64);
    if (lane >= d) x += y;
  }
  __shared__ int wsum[16];
  if (lane == 63) wsum[wid] = x;
  __syncthreads();
  if (t < 16) {
    int s = wsum[t];
    #pragma unroll
    for (int d = 1; d < 16; d <<= 1) {
      int y = __shfl_up(s, d, 16);
      if (t >= d) s += y;
    }
    wsum[t] = s;
  }
  __syncthreads();
  int woff = wid ? wsum[wid - 1] : 0;
  int o = b * E_ + woff + x - v;
  off[b * NPG + t] = o;
  cur[b * NPG + t] = o;
}

// ---------------- CSR fill ----------------
__global__ void k_build(const int* __restrict__ srcl, const int* __restrict__ dstl,
                        int* __restrict__ cur_in, int* __restrict__ cur_out,
                        int* __restrict__ ebd_src, int* __restrict__ ebs_dst) {
  int i = blockIdx.x * 256 + threadIdx.x;
  int b = i >> 14;
  int base = b << 10;
  int s = srcl[i] + base, d = dstl[i] + base;
  int p = atomicAdd(&cur_in[d], 1);
  ebd_src[p] = s;
  int q = atomicAdd(&cur_out[s], 1);
  ebs_dst[q] = d;
}

// ---------------- gather bf16 h rows -> c bf16; also zero a 16KB slice of adj ----------------
__global__ void k_gather_c(const unsigned short* __restrict__ hb, const int* __restrict__ elist,
                           const int* __restrict__ off, const int* __restrict__ deg,
                           unsigned short* __restrict__ cb, float* __restrict__ adj) {
  // fire-and-forget zeroing of this block's adj slice (overlaps with gather latency)
  {
    float4 z4 = make_float4(0.f, 0.f, 0.f, 0.f);
    float4* dst = reinterpret_cast<float4*>(adj) + (size_t)blockIdx.x * 1024 + threadIdx.x;
    #pragma unroll
    for (int r = 0; r < 4; ++r) dst[r * 256] = z4;
  }
  int w = threadIdx.x >> 6, lane = threadIdx.x & 63;
  int node = blockIdx.x * 4 + w;
  int o = off[node], d = deg[node];
  float accx = 0.f, accy = 0.f;
  int e = o, end = o + d;
  while (e < end) {
    int cnt = end - e; if (cnt > 64) cnt = 64;
    int sidx = (lane < cnt) ? elist[e + lane] : 0;
    for (int j = 0; j < cnt; ++j) {
      int s = __shfl(sidx, j, 64);
      unsigned v = *reinterpret_cast<const unsigned*>(hb + (size_t)s * 128 + lane * 2);
      accx += __uint_as_float((v & 0xffffu) << 16);
      accy += __uint_as_float(v & 0xffff0000u);
    }
    e += cnt;
  }
  float inv = 1.0f / fmaxf((float)d, 1.0f);
  accx *= inv; accy *= inv;
  unsigned ov = (unsigned)f2b(accx) | ((unsigned)f2b(accy) << 16);
  *reinterpret_cast<unsigned*>(cb + (size_t)node * 128 + lane * 2) = ov;
}

// ---------------- gather bf16 assign rows (stride 256) -> AS bf16 ----------------
__global__ void k_gather_as(const unsigned short* __restrict__ rows, const int* __restrict__ elist,
                            const int* __restrict__ off, const int* __restrict__ deg,
                            unsigned short* __restrict__ outb) {
  int w = threadIdx.x >> 6, lane = threadIdx.x & 63;
  int node = blockIdx.x * 4 + w;
  int o = off[node], d = deg[node];
  float accx = 0.f, accy = 0.f;
  int e = o, end = o + d;
  while (e < end) {
    int cnt = end - e; if (cnt > 64) cnt = 64;
    int sidx = (lane < cnt) ? elist[e + lane] : 0;
    for (int j = 0; j < cnt; ++j) {
      int s = __shfl(sidx, j, 64);
      unsigned v = *reinterpret_cast<const unsigned*>(rows + (size_t)s * 256 + lane * 2);
      accx += __uint_as_float((v & 0xffffu) << 16);
      accy += __uint_as_float(v & 0xffff0000u);
    }
    e += cnt;
  }
  unsigned ov = (unsigned)f2b(accx) | ((unsigned)f2b(accy) << 16);
  *reinterpret_cast<unsigned*>(outb + (size_t)node * 128 + lane * 2) = ov;
}

// ---------------- W transpose+cvt: Wt[j][k] bf16 ----------------
__global__ void k_wt(const float* __restrict__ Wf, const float* __restrict__ Wp,
                     __bf16* __restrict__ Wt) {
  int j = blockIdx.x;
  int k = threadIdx.x;
  const float* W = (j < 128) ? Wf : Wp;
  int jj = j & 127;
  Wt[j * 256 + k] = (__bf16)W[k * 128 + jj];
}

// ---------------- MFMA GEMM + fused l2norm/relu/softmax epilogue, bf16 Z out ----------------
__global__ __launch_bounds__(512) void k_gemm(const __bf16* __restrict__ hb,
                                              const __bf16* __restrict__ cb,
                                              const __bf16* __restrict__ Wt,
                                              const float* __restrict__ bfeat,
                                              const float* __restrict__ bpool,
                                              __bf16* __restrict__ Z) {
  __shared__ char smem[69632];
  __bf16* A_lds = (__bf16*)smem;            // [128][32]
  __bf16* B_lds = (__bf16*)(smem + 8192);   // [256][40]
  const int t = threadIdx.x;
  const int wid = t >> 6, lane = t & 63;
  const int wm = wid >> 1, wn = wid & 1;
  const int lo = lane & 15, hi = lane >> 4;
  const int m0 = blockIdx.x * 128;

  float bias[8];
  const float* bsrc = wn ? bpool : bfeat;
  #pragma unroll
  for (int nf = 0; nf < 8; ++nf) bias[nf] = bsrc[nf * 16 + lo];

  f32x4 acc[2][8];
  #pragma unroll
  for (int mf = 0; mf < 2; ++mf)
    #pragma unroll
    for (int nf = 0; nf < 8; ++nf) acc[mf][nf] = (f32x4){0.f, 0.f, 0.f, 0.f};

  const int am = t >> 2, akq = (t & 3) * 8;
  const int bj = t >> 1, bh = (t & 1) * 16;

  for (int ks = 0; ks < 8; ++ks) {
    const int kb = ks * 32;
    const __bf16* __restrict__ X = (kb < 128) ? hb : cb;
    const int kbb = kb & 127;
    *reinterpret_cast<bf16x8*>(A_lds + am * 32 + akq) =
        *reinterpret_cast<const bf16x8*>(X + (size_t)(m0 + am) * 128 + kbb + akq);
    {
      bf16x8 b0 = *reinterpret_cast<const bf16x8*>(Wt + bj * 256 + kb + bh);
      bf16x8 b1 = *reinterpret_cast<const bf16x8*>(Wt + bj * 256 + kb + bh + 8);
      *reinterpret_cast<bf16x8*>(B_lds + bj * 40 + bh) = b0;
      *reinterpret_cast<bf16x8*>(B_lds + bj * 40 + bh + 8) = b1;
    }
    __syncthreads();
    bf16x8 a[2], b[8];
    #pragma unroll
    for (int mf = 0; mf < 2; ++mf)
      a[mf] = *reinterpret_cast<const bf16x8*>(A_lds + (wm * 32 + mf * 16 + lo) * 32 + hi * 8);
    #pragma unroll
    for (int nf = 0; nf < 8; ++nf)
      b[nf] = *reinterpret_cast<const bf16x8*>(B_lds + (wn * 128 + nf * 16 + lo) * 40 + hi * 8);
    #pragma unroll
    for (int mf = 0; mf < 2; ++mf)
      #pragma unroll
      for (int nf = 0; nf < 8; ++nf)
        acc[mf][nf] = __builtin_amdgcn_mfma_f32_16x16x32_bf16(a[mf], b[nf], acc[mf][nf], 0, 0, 0);
    __syncthreads();
  }

  __bf16* obuf = (__bf16*)(smem + wid * 8704);    // per-wave [32][136]
  #pragma unroll
  for (int mf = 0; mf < 2; ++mf) {
    #pragma unroll
    for (int r = 0; r < 4; ++r) {
      float v[8];
      #pragma unroll
      for (int nf = 0; nf < 8; ++nf) v[nf] = acc[mf][nf][r] + bias[nf];
      float ss = 0.f;
      #pragma unroll
      for (int nf = 0; nf < 8; ++nf) ss += v[nf] * v[nf];
      ss += __shfl_xor(ss, 1, 64); ss += __shfl_xor(ss, 2, 64);
      ss += __shfl_xor(ss, 4, 64); ss += __shfl_xor(ss, 8, 64);
      float rn = 1.0f / fmaxf(sqrtf(ss), 1e-12f);
      #pragma unroll
      for (int nf = 0; nf < 8; ++nf) v[nf] = fmaxf(v[nf] * rn, 0.f);
      if (wn) {
        float mx = v[0];
        #pragma unroll
        for (int nf = 1; nf < 8; ++nf) mx = fmaxf(mx, v[nf]);
        mx = fmaxf(mx, __shfl_xor(mx, 1, 64)); mx = fmaxf(mx, __shfl_xor(mx, 2, 64));
        mx = fmaxf(mx, __shfl_xor(mx, 4, 64)); mx = fmaxf(mx, __shfl_xor(mx, 8, 64));
        float es = 0.f;
        #pragma unroll
        for (int nf = 0; nf < 8; ++nf) { v[nf] = __expf(v[nf] - mx); es += v[nf]; }
        es += __shfl_xor(es, 1, 64); es += __shfl_xor(es, 2, 64);
        es += __shfl_xor(es, 4, 64); es += __shfl_xor(es, 8, 64);
        float inv = 1.0f / es;
        #pragma unroll
        for (int nf = 0; nf < 8; ++nf) v[nf] *= inv;
      }
      int row = mf * 16 + hi * 4 + r;
      #pragma unroll
      for (int nf = 0; nf < 8; ++nf) obuf[row * 136 + nf * 16 + lo] = (__bf16)v[nf];
    }
  }
  __syncthreads();
  #pragma unroll
  for (int i = 0; i < 8; ++i) {
    int r = i * 4 + hi;
    bf16x8 d = *reinterpret_cast<const bf16x8*>(obuf + r * 136 + lo * 8);
    int node = m0 + wm * 32 + r;
    *reinterpret_cast<bf16x8*>(Z + (size_t)node * 256 + wn * 128 + lo * 8) = d;
  }
}

// ---------------- per-graph S^T X partials: blk = b*8 + ch*4 + q ----------------
__global__ __launch_bounds__(256) void k_pool(const unsigned short* __restrict__ Zb,
                                              const unsigned short* __restrict__ ASb,
                                              float* __restrict__ part) {
  const int blk = blockIdx.x;
  const int b = blk >> 3, ch = (blk >> 2) & 1, q = blk & 3;
  const int n0 = b * NPG + q * 256;
  const unsigned short* __restrict__ Xbase = ch ? ASb : Zb;
  const int xstride = ch ? 128 : 256;
  __shared__ float Ss[16][128];
  __shared__ float Xs[16][128];
  const int t = threadIdx.x;
  const int tx = t & 15, ty = t >> 4;
  float acc[8][8];
  #pragma unroll
  for (int i = 0; i < 8; ++i)
    #pragma unroll
    for (int j = 0; j < 8; ++j) acc[i][j] = 0.f;

  for (int nc = 0; nc < 256; nc += 16) {
    #pragma unroll
    for (int r = 0; r < 2; ++r) {
      int idx = t * 2 + r;
      int nn = idx >> 5;
      int jq = (idx & 31) * 4;
      int n = n0 + nc + nn;
      ushort4 sv = *reinterpret_cast<const ushort4*>(Zb + (size_t)n * 256 + 128 + jq);
      *reinterpret_cast<float4*>(&Ss[nn][jq]) =
          make_float4(b2f(sv.x), b2f(sv.y), b2f(sv.z), b2f(sv.w));
      ushort4 xv = *reinterpret_cast<const ushort4*>(Xbase + (size_t)n * xstride + jq);
      *reinterpret_cast<float4*>(&Xs[nn][jq]) =
          make_float4(b2f(xv.x), b2f(xv.y), b2f(xv.z), b2f(xv.w));
    }
    __syncthreads();
    #pragma unroll
    for (int nn = 0; nn < 16; ++nn) {
      float a[8], x[8];
      #pragma unroll
      for (int i = 0; i < 8; ++i) a[i] = Ss[nn][ty * 8 + i];
      #pragma unroll
      for (int j = 0; j < 8; ++j) x[j] = Xs[nn][tx * 8 + j];
      #pragma unroll
      for (int i = 0; i < 8; ++i)
        #pragma unroll
        for (int j = 0; j < 8; ++j) acc[i][j] += a[i] * x[j];
    }
    __syncthreads();
  }
  float* dst = part + (size_t)blk * 16384;
  #pragma unroll
  for (int i = 0; i < 8; ++i) {
    *reinterpret_cast<float4*>(dst + (ty * 8 + i) * 128 + tx * 8) =
        make_float4(acc[i][0], acc[i][1], acc[i][2], acc[i][3]);
    *reinterpret_cast<float4*>(dst + (ty * 8 + i) * 128 + tx * 8 + 4) =
        make_float4(acc[i][4], acc[i][5], acc[i][6], acc[i][7]);
  }
}

// ---------------- combine q partials -> h_new (final) and blocks (ws) ----------------
__global__ void k_reduce(const float* __restrict__ part, float* __restrict__ h_new,
                         float* __restrict__ blocks) {
  int i = blockIdx.x * 256 + threadIdx.x;   // 2,097,152
  int bc = i >> 14;
  int r = i & 16383;
  int b = bc >> 1, ch = bc & 1;
  size_t base = ((size_t)(b * 8 + ch * 4)) * 16384 + r;
  float v = part[base] + part[base + 16384] + part[base + 32768] + part[base + 49152];
  if (ch == 0) h_new[(size_t)b * 16384 + r] = v;
  else blocks[(size_t)b * 16384 + r] = v;
}

// ---------------- scatter diagonal blocks into zeroed adj ----------------
__global__ void k_scatter(const float* __restrict__ blocks, float* __restrict__ adj) {
  int i = blockIdx.x * 256 + threadIdx.x;
  int b = i >> 14;
  int k = (i >> 7) & 127;
  int l = i & 127;
  adj[(size_t)(b * 128 + k) * ADJ_DIM + b * 128 + l] = blocks[i];
}

extern "C" void kernel_launch(void* const* d_in, const int* in_sizes, int n_in,
                              void* d_out, int out_size, void* d_ws, size_t ws_size,
                              hipStream_t stream) {
  (void)in_sizes; (void)n_in; (void)out_size; (void)ws_size;
  const float* h   = (const float*)d_in[0];
  const int* srcl  = (const int*)d_in[1];
  const int* dstl  = (const int*)d_in[2];
  const float* Wf  = (const float*)d_in[3];
  const float* bfe = (const float*)d_in[4];
  const float* Wp  = (const float*)d_in[5];
  const float* bpo = (const float*)d_in[6];

  float* out   = (float*)d_out;
  float* adj   = out;                 // 268 MB, zeroed inside k_gather_c, diagonal by k_scatter
  float* h_new = out + ADJ_ELEMS;

  // ---- all scratch in d_ws (~132 MB used; ws ≈ 1.09 GB) ----
  char* W = (char*)d_ws;
  int* deg_in   = (int*)W;                          // 65536
  int* deg_out  = deg_in + N_;
  int* off_in   = deg_out + N_;
  int* cur_in   = off_in + N_;
  int* off_out  = cur_in + N_;
  int* cur_out  = off_out + N_;
  int* ebd_src  = cur_out + N_;                     // 1,048,576
  int* ebs_dst  = ebd_src + BE_;                    // 1,048,576
  unsigned short* hb  = (unsigned short*)(ebs_dst + BE_);   //  8,388,608 bf16
  unsigned short* cb  = hb + 8388608UL;                     //  8,388,608 bf16
  unsigned short* Zb  = cb + 8388608UL;                     // 16,777,216 bf16
  unsigned short* ASb = Zb + 16777216UL;                    //  8,388,608 bf16
  __bf16* Wt          = (__bf16*)(ASb + 8388608UL);         //     65,536 bf16
  float* part         = (float*)((unsigned short*)Wt + 65536UL); // 8,388,608 f32
  float* blocks       = part + 8388608UL;                   //  1,048,576 f32

  hipMemsetAsync(deg_in, 0, 2UL * N_ * sizeof(int), stream);
  k_hbf<<<8192, 256, 0, stream>>>(h, hb);
  k_wt<<<256, 256, 0, stream>>>(Wf, Wp, Wt);
  k_count<<<BE_ / 256, 256, 0, stream>>>(srcl, dstl, deg_in, deg_out);
  k_scan<<<B_, 1024, 0, stream>>>(deg_in, off_in, cur_in);
  k_scan<<<B_, 1024, 0, stream>>>(deg_out, off_out, cur_out);
  k_build<<<BE_ / 256, 256, 0, stream>>>(srcl, dstl, cur_in, cur_out, ebd_src, ebs_dst);
  k_gather_c<<<N_ / 4, 256, 0, stream>>>(hb, ebd_src, off_in, deg_in, cb, adj);
  k_gemm<<<N_ / 128, 512, 0, stream>>>((const __bf16*)hb, (const __bf16*)cb, Wt, bfe, bpo, (__bf16*)Zb);
  k_gather_as<<<N_ / 4, 256, 0, stream>>>(Zb + 128, ebs_dst, off_out, deg_out, ASb);
  k_pool<<<512, 256, 0, stream>>>(Zb, ASb, part);
  k_reduce<<<8192, 256, 0, stream>>>(part, h_new, blocks);
  k_scatter<<<4096, 256, 0, stream>>>(blocks, adj);
}

// Round 7
// 570.089 us; speedup vs baseline: 1.3918x; 1.1475x over previous
//
#include <hip/hip_runtime.h>
#include <hip/hip_bf16.h>
#include <cstddef>

#define B_    64
#define NPG   1024
#define F_    128
#define K_    128
#define E_    16384
#define N_    (B_*NPG)        // 65536
#define BE_   (B_*E_)         // 1048576
#define ADJ_DIM 8192
#define ADJ_ELEMS 67108864UL  // 8192*8192

typedef __bf16 bf16x8 __attribute__((ext_vector_type(8)));
typedef float  f32x4  __attribute__((ext_vector_type(4)));
typedef unsigned short u16x8 __attribute__((ext_vector_type(8)));

__device__ inline unsigned short f2b(float f) {
  __bf16 b = (__bf16)f;
  return *reinterpret_cast<unsigned short*>(&b);
}
__device__ inline unsigned packbf(float x, float y) {
  return (unsigned)f2b(x) | ((unsigned)f2b(y) << 16);
}
__device__ inline void addrow(float* a, uint4 v) {
  a[0] += __uint_as_float(v.x << 16);
  a[1] += __uint_as_float(v.x & 0xffff0000u);
  a[2] += __uint_as_float(v.y << 16);
  a[3] += __uint_as_float(v.y & 0xffff0000u);
  a[4] += __uint_as_float(v.z << 16);
  a[5] += __uint_as_float(v.z & 0xffff0000u);
  a[6] += __uint_as_float(v.w << 16);
  a[7] += __uint_as_float(v.w & 0xffff0000u);
}

// ---------------- h -> bf16 ----------------
__global__ void k_hbf(const float* __restrict__ h, unsigned short* __restrict__ hb) {
  int i = blockIdx.x * 256 + threadIdx.x;
  float4 v = reinterpret_cast<const float4*>(h)[i];
  ushort4 o;
  o.x = f2b(v.x); o.y = f2b(v.y); o.z = f2b(v.z); o.w = f2b(v.w);
  reinterpret_cast<ushort4*>(hb)[i] = o;
}

// ---------------- edge counting ----------------
__global__ void k_count(const int* __restrict__ srcl, const int* __restrict__ dstl,
                        int* __restrict__ deg_in, int* __restrict__ deg_out) {
  int i = blockIdx.x * 256 + threadIdx.x;
  int b = i >> 14;
  int base = b << 10;
  atomicAdd(&deg_in[dstl[i] + base], 1);
  atomicAdd(&deg_out[srcl[i] + base], 1);
}

// ---------------- per-graph exclusive scan ----------------
__global__ __launch_bounds__(1024) void k_scan(const int* __restrict__ deg,
                                               int* __restrict__ off, int* __restrict__ cur) {
  int b = blockIdx.x, t = threadIdx.x;
  int v = deg[b * NPG + t];
  int lane = t & 63, wid = t >> 6;
  int x = v;
  #pragma unroll
  for (int d = 1; d < 64; d <<= 1) {
    int y = __shfl_up(x, d, 64);
    if (lane >= d) x += y;
  }
  __shared__ int wsum[16];
  if (lane == 63) wsum[wid] = x;
  __syncthreads();
  if (t < 16) {
    int s = wsum[t];
    #pragma unroll
    for (int d = 1; d < 16; d <<= 1) {
      int y = __shfl_up(s, d, 16);
      if (t >= d) s += y;
    }
    wsum[t] = s;
  }
  __syncthreads();
  int woff = wid ? wsum[wid - 1] : 0;
  int o = b * E_ + woff + x - v;
  off[b * NPG + t] = o;
  cur[b * NPG + t] = o;
}

// ---------------- CSR fill ----------------
__global__ void k_build(const int* __restrict__ srcl, const int* __restrict__ dstl,
                        int* __restrict__ cur_in, int* __restrict__ cur_out,
                        int* __restrict__ ebd_src, int* __restrict__ ebs_dst) {
  int i = blockIdx.x * 256 + threadIdx.x;
  int b = i >> 14;
  int base = b << 10;
  int s = srcl[i] + base, d = dstl[i] + base;
  int p = atomicAdd(&cur_in[d], 1);
  ebd_src[p] = s;
  int q = atomicAdd(&cur_out[s], 1);
  ebs_dst[q] = d;
}

// ---------------- gather: 4 edges concurrently per wave (16-lane groups) ----------------
// ROWSTRIDE in elements; MEAN divides by deg; ZERO also zeroes an adj slice.
template<int ROWSTRIDE, bool MEAN, bool ZERO>
__global__ void k_gather(const unsigned short* __restrict__ rows, const int* __restrict__ elist,
                         const int* __restrict__ off, const int* __restrict__ deg,
                         unsigned short* __restrict__ outb, float* __restrict__ adj) {
  if (ZERO) {
    float4 z4 = make_float4(0.f, 0.f, 0.f, 0.f);
    float4* dst = reinterpret_cast<float4*>(adj) + (size_t)blockIdx.x * 1024 + threadIdx.x;
    #pragma unroll
    for (int r = 0; r < 4; ++r) dst[r * 256] = z4;
  }
  int w = threadIdx.x >> 6, lane = threadIdx.x & 63;
  int g = lane >> 4, li = lane & 15;
  int node = blockIdx.x * 4 + w;
  int o = off[node], d = deg[node];
  float acc[8];
  #pragma unroll
  for (int i = 0; i < 8; ++i) acc[i] = 0.f;
  const unsigned short* rbase = rows + li * 8;
  int e = o, end = o + d;
  while (e < end) {
    int cnt = end - e; if (cnt > 64) cnt = 64;
    int sidx = (lane < cnt) ? elist[e + lane] : 0;
    for (int t = 0; t * 4 < cnt; ++t) {
      int j = t * 4 + g;
      int s = __shfl(sidx, j, 64);
      if (j < cnt) {
        uint4 v = *reinterpret_cast<const uint4*>(rbase + (size_t)s * ROWSTRIDE);
        addrow(acc, v);
      }
    }
    e += cnt;
  }
  #pragma unroll
  for (int i = 0; i < 8; ++i) {
    acc[i] += __shfl_xor(acc[i], 16, 64);
    acc[i] += __shfl_xor(acc[i], 32, 64);
  }
  if (g == 0) {
    float sc = MEAN ? (1.0f / fmaxf((float)d, 1.0f)) : 1.0f;
    uint4 ov;
    ov.x = packbf(acc[0] * sc, acc[1] * sc);
    ov.y = packbf(acc[2] * sc, acc[3] * sc);
    ov.z = packbf(acc[4] * sc, acc[5] * sc);
    ov.w = packbf(acc[6] * sc, acc[7] * sc);
    *reinterpret_cast<uint4*>(outb + (size_t)node * 128 + li * 8) = ov;
  }
}

// ---------------- W transpose+cvt: Wt[j][k] bf16 ----------------
__global__ void k_wt(const float* __restrict__ Wf, const float* __restrict__ Wp,
                     __bf16* __restrict__ Wt) {
  int j = blockIdx.x;
  int k = threadIdx.x;
  const float* W = (j < 128) ? Wf : Wp;
  int jj = j & 127;
  Wt[j * 256 + k] = (__bf16)W[k * 128 + jj];
}

// ---------------- MFMA GEMM + fused l2norm/relu/softmax epilogue, bf16 Z out ----------------
__global__ __launch_bounds__(512) void k_gemm(const __bf16* __restrict__ hb,
                                              const __bf16* __restrict__ cb,
                                              const __bf16* __restrict__ Wt,
                                              const float* __restrict__ bfeat,
                                              const float* __restrict__ bpool,
                                              __bf16* __restrict__ Z) {
  __shared__ char smem[69632];
  __bf16* A_lds = (__bf16*)smem;            // [128][32]
  __bf16* B_lds = (__bf16*)(smem + 8192);   // [256][40]
  const int t = threadIdx.x;
  const int wid = t >> 6, lane = t & 63;
  const int wm = wid >> 1, wn = wid & 1;
  const int lo = lane & 15, hi = lane >> 4;
  const int m0 = blockIdx.x * 128;

  float bias[8];
  const float* bsrc = wn ? bpool : bfeat;
  #pragma unroll
  for (int nf = 0; nf < 8; ++nf) bias[nf] = bsrc[nf * 16 + lo];

  f32x4 acc[2][8];
  #pragma unroll
  for (int mf = 0; mf < 2; ++mf)
    #pragma unroll
    for (int nf = 0; nf < 8; ++nf) acc[mf][nf] = (f32x4){0.f, 0.f, 0.f, 0.f};

  const int am = t >> 2, akq = (t & 3) * 8;
  const int bj = t >> 1, bh = (t & 1) * 16;

  for (int ks = 0; ks < 8; ++ks) {
    const int kb = ks * 32;
    const __bf16* __restrict__ X = (kb < 128) ? hb : cb;
    const int kbb = kb & 127;
    *reinterpret_cast<bf16x8*>(A_lds + am * 32 + akq) =
        *reinterpret_cast<const bf16x8*>(X + (size_t)(m0 + am) * 128 + kbb + akq);
    {
      bf16x8 b0 = *reinterpret_cast<const bf16x8*>(Wt + bj * 256 + kb + bh);
      bf16x8 b1 = *reinterpret_cast<const bf16x8*>(Wt + bj * 256 + kb + bh + 8);
      *reinterpret_cast<bf16x8*>(B_lds + bj * 40 + bh) = b0;
      *reinterpret_cast<bf16x8*>(B_lds + bj * 40 + bh + 8) = b1;
    }
    __syncthreads();
    bf16x8 a[2], b[8];
    #pragma unroll
    for (int mf = 0; mf < 2; ++mf)
      a[mf] = *reinterpret_cast<const bf16x8*>(A_lds + (wm * 32 + mf * 16 + lo) * 32 + hi * 8);
    #pragma unroll
    for (int nf = 0; nf < 8; ++nf)
      b[nf] = *reinterpret_cast<const bf16x8*>(B_lds + (wn * 128 + nf * 16 + lo) * 40 + hi * 8);
    #pragma unroll
    for (int mf = 0; mf < 2; ++mf)
      #pragma unroll
      for (int nf = 0; nf < 8; ++nf)
        acc[mf][nf] = __builtin_amdgcn_mfma_f32_16x16x32_bf16(a[mf], b[nf], acc[mf][nf], 0, 0, 0);
    __syncthreads();
  }

  __bf16* obuf = (__bf16*)(smem + wid * 8704);    // per-wave [32][136]
  #pragma unroll
  for (int mf = 0; mf < 2; ++mf) {
    #pragma unroll
    for (int r = 0; r < 4; ++r) {
      float v[8];
      #pragma unroll
      for (int nf = 0; nf < 8; ++nf) v[nf] = acc[mf][nf][r] + bias[nf];
      float ss = 0.f;
      #pragma unroll
      for (int nf = 0; nf < 8; ++nf) ss += v[nf] * v[nf];
      ss += __shfl_xor(ss, 1, 64); ss += __shfl_xor(ss, 2, 64);
      ss += __shfl_xor(ss, 4, 64); ss += __shfl_xor(ss, 8, 64);
      float rn = 1.0f / fmaxf(sqrtf(ss), 1e-12f);
      #pragma unroll
      for (int nf = 0; nf < 8; ++nf) v[nf] = fmaxf(v[nf] * rn, 0.f);
      if (wn) {
        float mx = v[0];
        #pragma unroll
        for (int nf = 1; nf < 8; ++nf) mx = fmaxf(mx, v[nf]);
        mx = fmaxf(mx, __shfl_xor(mx, 1, 64)); mx = fmaxf(mx, __shfl_xor(mx, 2, 64));
        mx = fmaxf(mx, __shfl_xor(mx, 4, 64)); mx = fmaxf(mx, __shfl_xor(mx, 8, 64));
        float es = 0.f;
        #pragma unroll
        for (int nf = 0; nf < 8; ++nf) { v[nf] = __expf(v[nf] - mx); es += v[nf]; }
        es += __shfl_xor(es, 1, 64); es += __shfl_xor(es, 2, 64);
        es += __shfl_xor(es, 4, 64); es += __shfl_xor(es, 8, 64);
        float inv = 1.0f / es;
        #pragma unroll
        for (int nf = 0; nf < 8; ++nf) v[nf] *= inv;
      }
      int row = mf * 16 + hi * 4 + r;
      #pragma unroll
      for (int nf = 0; nf < 8; ++nf) obuf[row * 136 + nf * 16 + lo] = (__bf16)v[nf];
    }
  }
  __syncthreads();
  #pragma unroll
  for (int i = 0; i < 8; ++i) {
    int r = i * 4 + hi;
    bf16x8 d = *reinterpret_cast<const bf16x8*>(obuf + r * 136 + lo * 8);
    int node = m0 + wm * 32 + r;
    *reinterpret_cast<bf16x8*>(Z + (size_t)node * 256 + wn * 128 + lo * 8) = d;
  }
}

// ---------------- MFMA pool: D[k][f] = sum_n S[n][k] * X[n][f] ----------------
// grid 256: blk = b*4 + ch*2 + nh. Contraction over 512 nodes; atomicAdd 2 partials.
__global__ __launch_bounds__(256) void k_poolm(const unsigned short* __restrict__ Zb,
                                               const unsigned short* __restrict__ ASb,
                                               float* __restrict__ h_new,
                                               float* __restrict__ adj) {
  const int blk = blockIdx.x;
  const int b = blk >> 2, ch = (blk >> 1) & 1, nh = blk & 1;
  const int n0 = b * NPG + nh * 512;
  __shared__ __align__(16) unsigned short ST[128 * 40];
  __shared__ __align__(16) unsigned short XT[128 * 40];
  const int t = threadIdx.x;
  const int wid = t >> 6, lane = t & 63;
  const int lo = lane & 15, hi = lane >> 4;
  const int wk = wid >> 1, wf = wid & 1;       // wave tile origin (k, f) = (wk*64, wf*64)
  const int sn = t & 31, sc0 = (t >> 5) * 16;  // staging: node-in-chunk, col base

  f32x4 acc[4][4];
  #pragma unroll
  for (int m = 0; m < 4; ++m)
    #pragma unroll
    for (int f = 0; f < 4; ++f) acc[m][f] = (f32x4){0.f, 0.f, 0.f, 0.f};

  for (int nc = 0; nc < 512; nc += 32) {
    int n = n0 + nc + sn;
    // stage S^T: S[n][c] = Zb[n*256 + 128 + c]
    {
      u16x8 s0 = *reinterpret_cast<const u16x8*>(Zb + (size_t)n * 256 + 128 + sc0);
      u16x8 s1 = *reinterpret_cast<const u16x8*>(Zb + (size_t)n * 256 + 128 + sc0 + 8);
      #pragma unroll
      for (int i = 0; i < 8; ++i) ST[(sc0 + i) * 40 + sn] = s0[i];
      #pragma unroll
      for (int i = 0; i < 8; ++i) ST[(sc0 + 8 + i) * 40 + sn] = s1[i];
    }
    // stage X^T: X = ch ? ASb[n][c] : Zb[n*256 + c]
    {
      const unsigned short* xr = ch ? (ASb + (size_t)n * 128 + sc0)
                                    : (Zb + (size_t)n * 256 + sc0);
      u16x8 x0 = *reinterpret_cast<const u16x8*>(xr);
      u16x8 x1 = *reinterpret_cast<const u16x8*>(xr + 8);
      #pragma unroll
      for (int i = 0; i < 8; ++i) XT[(sc0 + i) * 40 + sn] = x0[i];
      #pragma unroll
      for (int i = 0; i < 8; ++i) XT[(sc0 + 8 + i) * 40 + sn] = x1[i];
    }
    __syncthreads();
    bf16x8 a[4], bb[4];
    #pragma unroll
    for (int m = 0; m < 4; ++m)
      a[m] = *reinterpret_cast<const bf16x8*>(ST + (wk * 64 + m * 16 + lo) * 40 + hi * 8);
    #pragma unroll
    for (int f = 0; f < 4; ++f)
      bb[f] = *reinterpret_cast<const bf16x8*>(XT + (wf * 64 + f * 16 + lo) * 40 + hi * 8);
    #pragma unroll
    for (int m = 0; m < 4; ++m)
      #pragma unroll
      for (int f = 0; f < 4; ++f)
        acc[m][f] = __builtin_amdgcn_mfma_f32_16x16x32_bf16(a[m], bb[f], acc[m][f], 0, 0, 0);
    __syncthreads();
  }

  if (ch == 0) {
    #pragma unroll
    for (int m = 0; m < 4; ++m)
      #pragma unroll
      for (int f = 0; f < 4; ++f)
        #pragma unroll
        for (int r = 0; r < 4; ++r) {
          int k = wk * 64 + m * 16 + hi * 4 + r;
          int fc = wf * 64 + f * 16 + lo;
          atomicAdd(&h_new[(size_t)(b * 128 + k) * 128 + fc], acc[m][f][r]);
        }
  } else {
    #pragma unroll
    for (int m = 0; m < 4; ++m)
      #pragma unroll
      for (int f = 0; f < 4; ++f)
        #pragma unroll
        for (int r = 0; r < 4; ++r) {
          int k = wk * 64 + m * 16 + hi * 4 + r;
          int fc = wf * 64 + f * 16 + lo;
          atomicAdd(&adj[(size_t)(b * 128 + k) * ADJ_DIM + b * 128 + fc], acc[m][f][r]);
        }
  }
}

extern "C" void kernel_launch(void* const* d_in, const int* in_sizes, int n_in,
                              void* d_out, int out_size, void* d_ws, size_t ws_size,
                              hipStream_t stream) {
  (void)in_sizes; (void)n_in; (void)out_size; (void)ws_size;
  const float* h   = (const float*)d_in[0];
  const int* srcl  = (const int*)d_in[1];
  const int* dstl  = (const int*)d_in[2];
  const float* Wf  = (const float*)d_in[3];
  const float* bfe = (const float*)d_in[4];
  const float* Wp  = (const float*)d_in[5];
  const float* bpo = (const float*)d_in[6];

  float* out   = (float*)d_out;
  float* adj   = out;                 // zeroed inside k_gather_c, diagonal written by k_poolm
  float* h_new = out + ADJ_ELEMS;     // zeroed by memset, accumulated by k_poolm

  char* W = (char*)d_ws;
  int* deg_in   = (int*)W;
  int* deg_out  = deg_in + N_;
  int* off_in   = deg_out + N_;
  int* cur_in   = off_in + N_;
  int* off_out  = cur_in + N_;
  int* cur_out  = off_out + N_;
  int* ebd_src  = cur_out + N_;                     // 1,048,576
  int* ebs_dst  = ebd_src + BE_;                    // 1,048,576
  unsigned short* hb  = (unsigned short*)(ebs_dst + BE_);   //  8,388,608 bf16
  unsigned short* cb  = hb + 8388608UL;                     //  8,388,608 bf16
  unsigned short* Zb  = cb + 8388608UL;                     // 16,777,216 bf16
  unsigned short* ASb = Zb + 16777216UL;                    //  8,388,608 bf16
  __bf16* Wt          = (__bf16*)(ASb + 8388608UL);         //     65,536 bf16

  hipMemsetAsync(deg_in, 0, 2UL * N_ * sizeof(int), stream);
  hipMemsetAsync(h_new, 0, (size_t)B_ * K_ * F_ * sizeof(float), stream);
  k_hbf<<<8192, 256, 0, stream>>>(h, hb);
  k_wt<<<256, 256, 0, stream>>>(Wf, Wp, Wt);
  k_count<<<BE_ / 256, 256, 0, stream>>>(srcl, dstl, deg_in, deg_out);
  k_scan<<<B_, 1024, 0, stream>>>(deg_in, off_in, cur_in);
  k_scan<<<B_, 1024, 0, stream>>>(deg_out, off_out, cur_out);
  k_build<<<BE_ / 256, 256, 0, stream>>>(srcl, dstl, cur_in, cur_out, ebd_src, ebs_dst);
  k_gather<128, true, true><<<N_ / 4, 256, 0, stream>>>(hb, ebd_src, off_in, deg_in, cb, adj);
  k_gemm<<<N_ / 128, 512, 0, stream>>>((const __bf16*)hb, (const __bf16*)cb, Wt, bfe, bpo, (__bf16*)Zb);
  k_gather<256, false, false><<<N_ / 4, 256, 0, stream>>>(Zb + 128, ebs_dst, off_out, deg_out, ASb, nullptr);
  k_poolm<<<256, 256, 0, stream>>>(Zb, ASb, h_new, adj);
}